// Round 6
// baseline (488.940 us; speedup 1.0000x reference)
//
#include <hip/hip_runtime.h>
#include <math.h>

#define NG 4096
#define M 50
#define KTOP 30
#define H 32
#define F_IN 128
#define EPG 400          // edges per graph (M * DEG)
#define PADE 552         // EPG + M*3: CSR rows padded to multiples of 4
#define E_TOTAL (NG * EPG)
#define DLAT 97
#define LATS 100         // padded stride for lat tile (16B-aligned rows)
#define NTHREADS 256

// workspace layout (floats) -- written by prep_kernel every launch
#define WS_WT0 0         // W0^T  [32][128]
#define WS_WT1 4096      // W1^T  [32][32]
#define WS_WT2 5120      // W2^T  [32][32]
#define WS_C1P 6144      // C1w padded [16][100] (cols 97..99 = 0)
#define WS_L1T 7744      // L1w^T [128][352]
#define WS_TOTAL 52800   // 211 KB

// fast tanh: 1 - 2/(e^{2x}+1). abs err ~1e-6; layers 1-3 only (layer 4 =
// sort key uses exact tanhf).
__device__ __forceinline__ float fast_tanh(float x) {
    x = fminf(fmaxf(x, -15.f), 15.f);
    float e = __expf(2.f * x);
    return 1.f - 2.f / (e + 1.f);
}

// ---- prep: transpose/pad weights into ws (ws is re-poisoned per launch) ----
__global__ void prep_kernel(const float* __restrict__ W0, const float* __restrict__ W1,
                            const float* __restrict__ W2, const float* __restrict__ C1w,
                            const float* __restrict__ L1w, float* __restrict__ ws) {
    const int tid = blockIdx.x * blockDim.x + threadIdx.x;
    const int nthr = gridDim.x * blockDim.x;
    for (int idx = tid; idx < 4096; idx += nthr) {
        int j = idx >> 7, k = idx & 127;
        ws[WS_WT0 + idx] = W0[k * 32 + j];
    }
    for (int idx = tid; idx < 1024; idx += nthr) {
        int j = idx >> 5, k = idx & 31;
        ws[WS_WT1 + idx] = W1[k * 32 + j];
        ws[WS_WT2 + idx] = W2[k * 32 + j];
    }
    for (int idx = tid; idx < 1600; idx += nthr) {
        int c = idx / 100, d = idx - c * 100;
        ws[WS_C1P + idx] = (d < DLAT) ? C1w[c * DLAT + d] : 0.f;
    }
    for (int idx = tid; idx < 45056; idx += nthr) {
        int j = idx / 352, f = idx - j * 352;
        ws[WS_L1T + idx] = L1w[f * 128 + j];
    }
}

// -------- GCN matmul (straight-line, transposed weights) ------------------
// tbuf[i][j] = sum_k hin[i*istride+k] * Wt[j*KIN+k]
// thread (iset = tid>>5, j = tid&31) owns rows {iset, iset+8, ..., iset+48};
// row 49 recomputed by 6 threads (clamp) -- keeps the k4 body branch-free.
// Per k4: 7 float4 hin loads + 1 float4 Wt load + 28 FMA.
template <int KIN>
__device__ __forceinline__ void gcn_matmul(const float* hin, int istride,
                                           const float* __restrict__ Wt,
                                           float (*tb)[H], int tid) {
    const int j = tid & 31, iset = tid >> 5;
    const float* wrow = Wt + j * KIN;
    float acc[7];
    int rows[7];
#pragma unroll
    for (int r = 0; r < 7; r++) {
        acc[r] = 0.f;
        int i = iset + r * 8;
        rows[r] = (i >= M) ? (M - 1) : i;
    }
#pragma unroll 2
    for (int k4 = 0; k4 < KIN / 4; k4++) {
        const float4 wv = *(const float4*)(wrow + 4 * k4);
#pragma unroll
        for (int r = 0; r < 7; r++) {
            const float4 xv = *(const float4*)(hin + rows[r] * istride + 4 * k4);
            acc[r] += xv.x * wv.x + xv.y * wv.y + xv.z * wv.z + xv.w * wv.w;
        }
    }
#pragma unroll
    for (int r = 0; r < 7; r++) {
        int i = iset + r * 8;
        if (i < M) tb[i][j] = acc[r];
    }
}

// aggregation + bias + tanh. Padded CSR: row extents are multiples of 4; one
// u32 load gives 4 packed u8 src ids, one b128 gives 4 norms, then 4
// INDEPENDENT tbuf reads -- 4x shorter dependent-LDS chain than scalar form.
__device__ __forceinline__ void gcn_agg(const float (*tbuf)[H], const float* __restrict__ b,
                                        float (*lat)[LATS], int col0,
                                        const float* dinv, const unsigned short* csr_off,
                                        const unsigned char* csr_src, const float* csr_nrm,
                                        int tid) {
    const int j = tid & 31, iset = tid >> 5;
    for (int i = iset; i < M; i += 8) {
        float acc = tbuf[i][j] * dinv[i] * dinv[i];   // self loop: norm = 1/deg
        int e0 = csr_off[i], e1 = csr_off[i + 1];
        for (int e = e0; e < e1; e += 4) {
            unsigned sp = *(const unsigned*)(csr_src + e);
            float4 nr = *(const float4*)(csr_nrm + e);
            acc += tbuf[sp & 255][j] * nr.x;
            acc += tbuf[(sp >> 8) & 255][j] * nr.y;
            acc += tbuf[(sp >> 16) & 255][j] * nr.z;
            acc += tbuf[sp >> 24][j] * nr.w;
        }
        lat[i][col0 + j] = fast_tanh(acc + b[j]);
    }
}

// (256,4): empirically the spill-free point (64 VGPR). (256,5) clamps the
// allocator to 48 VGPR -> 70 MB scratch spill (round-3 regression).
__global__ __launch_bounds__(NTHREADS, 4)
void dgcnn_kernel(const float* __restrict__ x, const int* __restrict__ eidx,
                  const float* __restrict__ ws,
                  const float* __restrict__ b0, const float* __restrict__ b1,
                  const float* __restrict__ b2,
                  const float* __restrict__ W3, const float* __restrict__ b3,
                  const float* __restrict__ C1b,
                  const float* __restrict__ C2w, const float* __restrict__ C2b,
                  const float* __restrict__ L1b,
                  const float* __restrict__ L2w, const float* __restrict__ L2b,
                  float* __restrict__ out) {
    // LDS total: 20000+6400+2208+552+104+200+200 = 29664 B -> 5 blocks/CU.
    __shared__ __align__(16) float lat[M][LATS];   // 20000 B
    // tbuf (pre-agg h@W) is dead after layer 4 -> tail buffers union into it.
    __shared__ __align__(16) union TU {            //  6400 B
        float tbuf[M][H];
        struct {
            float pbuf[16][15];                    //   960 B
            union {
                struct { float z1[16][KTOP]; unsigned char ord[52]; } a;
                struct { float z2[352]; float red[256]; } b;
            } u;
        } post;
    } tu;
    __shared__ __align__(16) float csr_nrm[PADE];  //  2208 B
    __shared__ unsigned char csr_src[PADE];        //   552 B
    __shared__ unsigned short csr_off[M + 2];      //   104 B
    __shared__ int   degi[M];                      //   200 B (becomes cursor)
    __shared__ float dinv[M];                      //   200 B

    const int g = blockIdx.x;
    const int tid = threadIdx.x;
    const int nbase = g * M;
    const int ebase = g * EPG;
    const float* xg = x + (size_t)nbase * F_IN;

    // ---- init: degrees, zero padded CSR, zero lat pad cols 97..99 ----
    if (tid < M) degi[tid] = 1;
    for (int idx = tid; idx < PADE; idx += NTHREADS) {
        csr_nrm[idx] = 0.f;
        csr_src[idx] = 0;
    }
    if (tid < 3 * M) lat[tid / 3][DLAT + tid % 3] = 0.f;   // pad: conv1 reads 100 cols
    __syncthreads();
    for (int e = tid; e < EPG; e += NTHREADS) {
        int d = eidx[E_TOTAL + ebase + e] - nbase;
        atomicAdd(&degi[d], 1);
    }
    __syncthreads();
    // ---- dinv + padded-CSR offsets (wave-0 shuffle scan); cursor=degi ----
    if (tid < M) dinv[tid] = rsqrtf((float)degi[tid]);
    if (tid < 64) {
        int cnt  = (tid < M) ? (degi[tid] - 1) : 0;
        int cntp = (cnt + 3) & ~3;
        int incl = cntp;
#pragma unroll
        for (int off = 1; off < 64; off <<= 1) {
            int nv = __shfl_up(incl, off);
            if (tid >= off) incl += nv;
        }
        if (tid < M) {
            csr_off[tid] = (unsigned short)(incl - cntp);
            degi[tid] = incl - cntp;
        }
        if (tid == M - 1) csr_off[M] = (unsigned short)incl;
    }
    __syncthreads();
    // ---- CSR fill (by dst); re-read eidx (L2-hot) ----
    for (int e = tid; e < EPG; e += NTHREADS) {
        int s = eidx[ebase + e] - nbase;
        int d = eidx[E_TOTAL + ebase + e] - nbase;
        float nr = dinv[s] * dinv[d];
        int pos = atomicAdd(&degi[d], 1);
        csr_src[pos] = (unsigned char)s;
        csr_nrm[pos] = nr;
    }
    __syncthreads();

    // ---- layer 1: x[50,128] (global) @ W0^T -> agg -> lat[:,0:32] ----
    gcn_matmul<F_IN>(xg, F_IN, ws + WS_WT0, tu.tbuf, tid);
    __syncthreads();
    gcn_agg(tu.tbuf, b0, lat, 0, dinv, csr_off, csr_src, csr_nrm, tid);
    __syncthreads();
    // ---- layer 2 ----
    gcn_matmul<H>(&lat[0][0], LATS, ws + WS_WT1, tu.tbuf, tid);
    __syncthreads();
    gcn_agg(tu.tbuf, b1, lat, 32, dinv, csr_off, csr_src, csr_nrm, tid);
    __syncthreads();
    // ---- layer 3 ----
    gcn_matmul<H>(&lat[0][32], LATS, ws + WS_WT2, tu.tbuf, tid);
    __syncthreads();
    gcn_agg(tu.tbuf, b2, lat, 64, dinv, csr_off, csr_src, csr_nrm, tid);
    __syncthreads();
    // ---- layer 4 (H -> 1): exact tanhf (sort key) ----
    if (tid < M) {
        float acc = 0.f;
        for (int k = 0; k < H; k++) acc += lat[tid][64 + k] * W3[k];
        tu.tbuf[tid][0] = acc;
    }
    __syncthreads();
    if (tid < M) {
        float acc = tu.tbuf[tid][0] * dinv[tid] * dinv[tid];
        int e0 = csr_off[tid], e1 = csr_off[tid + 1];
        for (int e = e0; e < e1; e += 4) {
            unsigned sp = *(const unsigned*)(csr_src + e);
            float4 nr = *(const float4*)(csr_nrm + e);
            acc += tu.tbuf[sp & 255][0] * nr.x + tu.tbuf[(sp >> 8) & 255][0] * nr.y
                 + tu.tbuf[(sp >> 16) & 255][0] * nr.z + tu.tbuf[sp >> 24][0] * nr.w;
        }
        lat[tid][96] = tanhf(acc + b3[0]);
    }
    __syncthreads();

    // ---- sort-pool: stable descending rank over lat[:,96] ----
    // (tbuf dead from here; tail aliases live in tu.post)
    if (tid < M) {
        float v = lat[tid][96];
        int r = 0;
        for (int jj = 0; jj < M; jj++) {
            float vj = lat[jj][96];
            r += (vj > v) || (vj == v && jj < tid);
        }
        tu.post.u.a.ord[r] = (unsigned char)tid;
    }
    __syncthreads();

    // ---- Conv1d(1,16,97,stride 97) + ReLU, vectorized over d ----
    // t=idx>>4: 16 lanes share a row -> LDS b128 broadcast; C1p rows 16B-aligned.
    for (int idx = tid; idx < 16 * KTOP; idx += NTHREADS) {
        int t = idx >> 4, c = idx & 15;
        const float4* row = (const float4*)lat[tu.post.u.a.ord[t]];
        const float4* cw  = (const float4*)(ws + WS_C1P + c * LATS);
        float acc = 0.f;
#pragma unroll 5
        for (int q = 0; q < LATS / 4; q++) {
            float4 rv = row[q], wv = cw[q];
            acc += rv.x * wv.x + rv.y * wv.y + rv.z * wv.z + rv.w * wv.w;
        }
        tu.post.u.a.z1[c][t] = fmaxf(acc + C1b[c], 0.f);
    }
    __syncthreads();

    // ---- MaxPool1d(2,2) -> pbuf ----
    for (int idx = tid; idx < 16 * 15; idx += NTHREADS) {
        int c = idx / 15, t = idx - c * 15;
        tu.post.pbuf[c][t] = fmaxf(tu.post.u.a.z1[c][2 * t],
                                   tu.post.u.a.z1[c][2 * t + 1]);
    }
    __syncthreads();

    // ---- Conv1d(16,32,5) + ReLU, flatten f = o*11 + t (z1/ord dead) ----
    for (int idx = tid; idx < 352; idx += NTHREADS) {
        int o = idx / 11, t = idx - o * 11;
        float acc = C2b[o];
        for (int i = 0; i < 16; i++) {
#pragma unroll
            for (int k = 0; k < 5; k++)
                acc += tu.post.pbuf[i][t + k] * C2w[(o * 16 + i) * 5 + k];
        }
        tu.post.u.b.z2[idx] = fmaxf(acc, 0.f);
    }
    __syncthreads();

    // ---- Dense 352 -> 128 + ReLU: L1^T rows, float4, f-split over 2 halves ----
    {
        int jj = tid & 127, half = tid >> 7;
        const float4* lw = (const float4*)(ws + WS_L1T + jj * 352 + half * 176);
        const float4* zz = (const float4*)(tu.post.u.b.z2 + half * 176);
        float acc = (half == 0) ? L1b[jj] : 0.f;
#pragma unroll 4
        for (int q = 0; q < 44; q++) {
            float4 zv = zz[q], wv = lw[q];
            acc += zv.x * wv.x + zv.y * wv.y + zv.z * wv.z + zv.w * wv.w;
        }
        tu.post.u.b.red[tid] = acc;
    }
    __syncthreads();
    // ---- fuse ReLU + Dense 128 -> 1 ----
    if (tid < 128)
        tu.post.u.b.red[tid] = fmaxf(tu.post.u.b.red[tid] + tu.post.u.b.red[tid + 128],
                                     0.f) * L2w[tid];
    __syncthreads();
    if (tid < 64) {
        float v = tu.post.u.b.red[tid] + tu.post.u.b.red[tid + 64];
#pragma unroll
        for (int off = 32; off >= 1; off >>= 1)
            v += __shfl_down(v, off);
        if (tid == 0) out[g] = v + L2b[0];
    }
}

extern "C" void kernel_launch(void* const* d_in, const int* in_sizes, int n_in,
                              void* d_out, int out_size, void* d_ws, size_t ws_size,
                              hipStream_t stream) {
    const float* x    = (const float*)d_in[0];
    const int*   eidx = (const int*)d_in[1];
    // d_in[2] (batch) unused: graphs are contiguous equal-size blocks
    float* ws = (float*)d_ws;
    prep_kernel<<<64, 256, 0, stream>>>(
        (const float*)d_in[3],  (const float*)d_in[5],
        (const float*)d_in[7],  (const float*)d_in[11],
        (const float*)d_in[15], ws);
    dgcnn_kernel<<<NG, NTHREADS, 0, stream>>>(
        x, eidx, ws,
        (const float*)d_in[4],  (const float*)d_in[6],
        (const float*)d_in[8],
        (const float*)d_in[9],  (const float*)d_in[10],
        (const float*)d_in[12],
        (const float*)d_in[13], (const float*)d_in[14],
        (const float*)d_in[16],
        (const float*)d_in[17], (const float*)d_in[18],
        (float*)d_out);
}